// Round 1
// baseline (1149.357 us; speedup 1.0000x reference)
//
#include <hip/hip_runtime.h>
#include <math.h>

#define B_ROWS 262144
#define NA 128
#define D_COLS 256
#define EPS 1e-5f
#define NPART 4096   // B_ROWS / 64 row-blocks

// -------------------- Kernel 1: GEMM + column partial stats --------------------
// z[b,d] = sum_n x[b,n] * W[d,n] + bias[d]
// Tile: BM=64 rows x BN=64 cols, K=128 (full). 256 threads, 4x4 microtile.
// Also writes per-(row-block, column) partial sum and sum-of-squares.
__global__ __launch_bounds__(256, 2)
void k_gemm(const float* __restrict__ x, const float* __restrict__ W,
            const float* __restrict__ bias,
            float* __restrict__ z,
            float* __restrict__ psum,    // [256][NPART] column-major partials
            float* __restrict__ psumsq)  // [256][NPART]
{
    __shared__ float As[64 * 132];   // [m][k], row pad 132 (16B-aligned rows)
    __shared__ float Bs[64 * 132];   // [n][k], k XOR-swizzled per n

    const int bid = blockIdx.x;
    // XCD-chunked swizzle: blocks with bid%8==x run on XCD x (round-robin
    // dispatch); give each XCD a contiguous chunk of work so the 4 column
    // blocks of a row-block hit the same L2 (x-tile reuse).
    const int w  = (bid & 7) * 2048 + (bid >> 3);   // 16384 % 8 == 0 -> bijective
    const int rb = w >> 2;   // row block  [0,4096)
    const int cb = w & 3;    // col block  [0,4)

    const int tid = threadIdx.x;
    const float* xg = x + (size_t)rb * 64 * NA;   // 64x128 contiguous
    const float* wg = W + (size_t)cb * 64 * NA;   // 64x128 contiguous

    // Stage both tiles: 2048 float4 each, 8 per thread, fully coalesced.
    #pragma unroll
    for (int j = 0; j < 8; ++j) {
        int f = tid + j * 256;      // [0,2048)
        int m = f >> 5;             // row in tile
        int q = f & 31;             // float4 index along K
        float4 va = ((const float4*)xg)[f];
        float4 vb = ((const float4*)wg)[f];
        *(float4*)&As[m * 132 + 4 * q] = va;
        int sw = (m & 24) >> 1;     // {0,4,8,12} word-XOR: kills 8-way bank conflict on B reads
        *(float4*)&Bs[m * 132 + ((4 * q) ^ sw)] = vb;
    }
    __syncthreads();

    const int tx = tid & 15;   // col group
    const int ty = tid >> 4;   // row group

    float acc[4][4] = {};
    #pragma unroll 8
    for (int kq = 0; kq < 32; ++kq) {
        float4 av[4], bv[4];
        #pragma unroll
        for (int i = 0; i < 4; ++i) {
            int m = 4 * ty + i;
            av[i] = *(const float4*)&As[m * 132 + 4 * kq];
            int n = 4 * tx + i;
            int sw = (n & 24) >> 1;
            bv[i] = *(const float4*)&Bs[n * 132 + ((4 * kq) ^ sw)];
        }
        #pragma unroll
        for (int i = 0; i < 4; ++i)
            #pragma unroll
            for (int j = 0; j < 4; ++j)
                acc[i][j] += av[i].x * bv[j].x + av[i].y * bv[j].y
                           + av[i].z * bv[j].z + av[i].w * bv[j].w;
    }

    // bias (include in z AND in the stats)
    float bb[4];
    #pragma unroll
    for (int j = 0; j < 4; ++j) bb[j] = bias[cb * 64 + 4 * tx + j];
    #pragma unroll
    for (int i = 0; i < 4; ++i)
        #pragma unroll
        for (int j = 0; j < 4; ++j) acc[i][j] += bb[j];

    // store z (coalesced float4 per row)
    #pragma unroll
    for (int i = 0; i < 4; ++i) {
        size_t row = (size_t)rb * 64 + 4 * ty + i;
        float4 o = make_float4(acc[i][0], acc[i][1], acc[i][2], acc[i][3]);
        *(float4*)&z[row * D_COLS + cb * 64 + 4 * tx] = o;
    }

    // per-thread column partials over its 4 rows
    float s[4], q2[4];
    #pragma unroll
    for (int j = 0; j < 4; ++j) {
        s[j]  = acc[0][j] + acc[1][j] + acc[2][j] + acc[3][j];
        q2[j] = acc[0][j]*acc[0][j] + acc[1][j]*acc[1][j]
              + acc[2][j]*acc[2][j] + acc[3][j]*acc[3][j];
    }
    __syncthreads();             // done with As/Bs, reuse As for reduction
    float* redS = As;            // [16][64]
    float* redQ = As + 1024;     // [16][64]
    #pragma unroll
    for (int j = 0; j < 4; ++j) {
        redS[ty * 64 + 4 * tx + j] = s[j];
        redQ[ty * 64 + 4 * tx + j] = q2[j];
    }
    __syncthreads();
    if (tid < 64) {
        float ss = 0.f, qq = 0.f;
        #pragma unroll
        for (int t = 0; t < 16; ++t) {
            ss += redS[t * 64 + tid];
            qq += redQ[t * 64 + tid];
        }
        int c = cb * 64 + tid;
        psum[c * NPART + rb]   = ss;
        psumsq[c * NPART + rb] = qq;
    }
}

// -------------------- Kernel 2: finalize BN stats --------------------
// Per column: mean, biased var -> fold into affine  zn = A*z + Bc
__global__ __launch_bounds__(256)
void k_stats(const float* __restrict__ psum, const float* __restrict__ psumsq,
             const float* __restrict__ gamma, const float* __restrict__ beta,
             float* __restrict__ sAB)
{
    __shared__ float ls[256], lq[256];
    const int c = blockIdx.x, t = threadIdx.x;
    float s = 0.f, q = 0.f;
    for (int p = t; p < NPART; p += 256) {
        s += psum[c * NPART + p];
        q += psumsq[c * NPART + p];
    }
    ls[t] = s; lq[t] = q;
    __syncthreads();
    for (int off = 128; off; off >>= 1) {
        if (t < off) { ls[t] += ls[t + off]; lq[t] += lq[t + off]; }
        __syncthreads();
    }
    if (t == 0) {
        float mean = ls[0] / (float)B_ROWS;
        float var  = lq[0] / (float)B_ROWS - mean * mean;
        float rstd = rsqrtf(var + EPS);
        float A = rstd * gamma[c];
        sAB[c]       = A;
        sAB[256 + c] = beta[c] - mean * A;
    }
}

// -------------------- Kernel 3: BN-affine * prior -> sparsemax --------------------
// One wave (64 lanes) per row, 4 elements per lane.
// Michelot fixed-point: tau <- (sum_{v>tau} v - 1)/|{v>tau}|, support shrinks
// monotonically, exact solution in a handful of iterations.
__global__ __launch_bounds__(256)
void k_sparsemax(const float* __restrict__ z, const float* __restrict__ prior,
                 const float* __restrict__ sAB,
                 float* __restrict__ out_sm, float* __restrict__ out_np)
{
    const int wid  = threadIdx.x >> 6;
    const int lane = threadIdx.x & 63;
    const size_t row  = (size_t)blockIdx.x * 4 + wid;
    const size_t base = row * D_COLS + lane * 4;

    float4 zv = *(const float4*)&z[base];
    float4 pv = *(const float4*)&prior[base];
    float4 Av = *(const float4*)&sAB[lane * 4];
    float4 Bv = *(const float4*)&sAB[256 + lane * 4];

    float4 v;
    v.x = fmaf(zv.x, Av.x, Bv.x) * pv.x;
    v.y = fmaf(zv.y, Av.y, Bv.y) * pv.y;
    v.z = fmaf(zv.z, Av.z, Bv.z) * pv.z;
    v.w = fmaf(zv.w, Av.w, Bv.w) * pv.w;

    // initial: support = all 256
    float s = v.x + v.y + v.z + v.w;
    #pragma unroll
    for (int off = 32; off; off >>= 1) s += __shfl_xor(s, off);
    float kcur = 256.f;
    float tau  = (s - 1.f) / kcur;

    for (int it = 0; it < 64; ++it) {
        float sn = 0.f, cn = 0.f;
        if (v.x > tau) { sn += v.x; cn += 1.f; }
        if (v.y > tau) { sn += v.y; cn += 1.f; }
        if (v.z > tau) { sn += v.z; cn += 1.f; }
        if (v.w > tau) { sn += v.w; cn += 1.f; }
        #pragma unroll
        for (int off = 32; off; off >>= 1) {
            sn += __shfl_xor(sn, off);
            cn += __shfl_xor(cn, off);
        }
        if (cn == kcur) break;     // support stable -> tau is the fixed point
        kcur = cn;
        tau  = (sn - 1.f) / cn;
    }

    float4 o;
    o.x = fmaxf(v.x - tau, 0.f);
    o.y = fmaxf(v.y - tau, 0.f);
    o.z = fmaxf(v.z - tau, 0.f);
    o.w = fmaxf(v.w - tau, 0.f);
    *(float4*)&out_sm[base] = o;

    float4 np;
    np.x = pv.x * o.x; np.y = pv.y * o.y; np.z = pv.z * o.z; np.w = pv.w * o.w;
    *(float4*)&out_np[base] = np;
}

// -------------------- launcher --------------------
extern "C" void kernel_launch(void* const* d_in, const int* in_sizes, int n_in,
                              void* d_out, int out_size, void* d_ws, size_t ws_size,
                              hipStream_t stream) {
    const float* x     = (const float*)d_in[0];
    const float* prior = (const float*)d_in[1];
    const float* W     = (const float*)d_in[2];
    const float* bias  = (const float*)d_in[3];
    const float* gamma = (const float*)d_in[4];
    const float* beta  = (const float*)d_in[5];

    float* out = (float*)d_out;
    // z lives in d_out's first half (sm region) and is overwritten in-place
    // by kernel 3 (each element read then written by the same thread).
    float* z       = out;
    float* out_np  = out + (size_t)B_ROWS * D_COLS;
    // BN partials live in the new_prior region of d_out; consumed by k_stats
    // before kernel 3 overwrites that region.
    float* psum    = out_np;
    float* psumsq  = psum + 256 * NPART;
    // folded BN affine coefficients (512 floats) in d_ws
    float* sAB     = (float*)d_ws;

    k_gemm<<<dim3(16384), dim3(256), 0, stream>>>(x, W, bias, z, psum, psumsq);
    k_stats<<<dim3(256), dim3(256), 0, stream>>>(psum, psumsq, gamma, beta, sAB);
    k_sparsemax<<<dim3(B_ROWS / 4), dim3(256), 0, stream>>>(z, prior, sAB, out, out_np);
}